// Round 18
// baseline (126.973 us; speedup 1.0000x reference)
//
#include <hip/hip_runtime.h>
#include <hip/hip_bf16.h>

#define Tn 512
#define Bn 512
#define Kn 128
#define NUMCH 16    // numerator t-chunks (32 t each)

typedef __bf16 bf16_t;
typedef __bf16 bf16x8 __attribute__((ext_vector_type(8)));
typedef float f32x4 __attribute__((ext_vector_type(4)));
typedef unsigned int u32;
typedef u32 u32x2 __attribute__((ext_vector_type(2)));
typedef u32 u32x4 __attribute__((ext_vector_type(4)));

__device__ __forceinline__ u32 pack2bf(float a, float b) {
    bf16_t ha = (bf16_t)a, hb = (bf16_t)b;
    u32 ua = (u32)__builtin_bit_cast(unsigned short, ha);
    u32 ub = (u32)__builtin_bit_cast(unsigned short, hb);
    return ua | (ub << 16);
}

// ---------------- small pre: numerator partials (0..31, coalesced) +
//                  frag build (32..159) + out zeroing.  (r12-verified) ----------
// A-frag image: idx = (((dir*8 + m)*4 + ks)*64 + l)*8 + e
//   lane roles: c=l&15, g=l>>4;  k = 32*ks + 8*g + e
//   row j = J(m,c) = 32*(m>>1) + 4*(m&1) + 8*(c>>2) + (c&3)
//   dir 0 (fwd): A[j][k] = exp(trans[k][j]);  dir 1 (bwd): A[j][k] = exp(trans[j][k])
// J chosen so D's per-lane output IS the next step's B-frag layout (verified r1-r17).
__global__ __launch_bounds__(256)
void crf_small(const float* __restrict__ em, const int* __restrict__ tags,
               const int* __restrict__ mask, const float* __restrict__ trans,
               bf16_t* __restrict__ frags, float* __restrict__ numpart,
               int* __restrict__ cntpart, float* __restrict__ out)
{
    const int bid = blockIdx.x;
    const int tid = threadIdx.x;

    if (bid < 2*NUMCH) {               // ---- numerator partials, coalesced over b ----
        const int ch = bid >> 1, bh = bid & 1;
        const int b  = bh*256 + tid;   // lane-adjacent b -> coalesced mask/tags loads
        const int t0 = ch * (Tn / NUMCH);
        float s = 0.f;
        int cnt = 0;
        int tagprev = (t0 > 0) ? tags[(t0-1)*Bn + b] : 0;
        for (int t = t0; t < t0 + Tn/NUMCH; ++t) {
            const int mk = mask[t*Bn + b];
            const int tagcur = tags[t*Bn + b];
            if (mk != 0) {
                cnt++;
                if (t >= 1)
                    s += trans[tagprev*Kn + tagcur]
                       + em[(size_t)t*Bn*Kn + (size_t)b*Kn + tagcur];
            }
            tagprev = tagcur;
        }
        numpart[ch*Bn + b] = s;
        cntpart[ch*Bn + b] = cnt;
        return;
    }

    // ---- frag build: 128 blocks x 256 threads = 32768 elements ----
    const int b2 = bid - 2*NUMCH;
    if (b2 == 0 && tid == 0) out[0] = 0.f;
    const int idx = b2*256 + tid;
    const int e   = idx & 7;
    const int l   = (idx >> 3) & 63;
    const int ks  = (idx >> 9) & 3;
    const int m   = (idx >> 11) & 7;
    const int dir = (idx >> 14) & 1;
    const int c = l & 15, g = l >> 4;
    const int k = 32*ks + 8*g + e;
    const int j = 32*(m >> 1) + 4*(m & 1) + 8*(c >> 2) + (c & 3);
    const float v = (dir == 0) ? trans[k*Kn + j] : trans[j*Kn + k];
    frags[idx] = (bf16_t)__expf(v);
}

// ---------------- main: 256-block 8-wave j-split recurrence, 4-DEEP prefetch --------
// r17 base (256 blocks x 512 threads, 4 batches/block with lane duplication; step time
// proved latency-floor-bound, not volume-bound). Single change: em/mask prefetch depth
// 2 -> 4 (buffers 0..3, each advancing 4t; ~3000cy coverage vs ~1500) + the extra live
// registers force the allocator out of its serialized-tail minimum (VGPR 40 -> ~60).
// Unroll-by-4 aligns with the rescale period so rs stays static. All t in-bounds.
__global__ __launch_bounds__(512, 1)
void crf_main(const float* __restrict__ em, const int* __restrict__ maskp,
              const float* __restrict__ startT, const float* __restrict__ endT,
              const bf16_t* __restrict__ frags,
              float* __restrict__ vws, float* __restrict__ Cws)
{
    const int bid = blockIdx.x;          // 256 blocks
    const int dir = bid & 1;
    const int b0  = (bid >> 1) * 4;      // 4-batch group
    const int tid = threadIdx.x;
    const int mw  = tid >> 6;            // wave id = m-tile index 0..7
    const int l   = tid & 63;
    const int c = l & 15, g = l >> 4;
    const int batch = b0 + (c & 3);      // lanes c>=4 duplicate batch c&3
    const int ksw  = mw >> 1, half = mw & 1;
    const int bj   = 32*ksw + 4*half;    // base j of own 4 outputs (plus 8g)

    __shared__ __align__(16) u32x4 exchg[2][4][64];   // [parity][slice][lane]

    // resident E fragments for own m-tile
    bf16x8 af[4];
    {
        const bf16_t* fb = frags + (size_t)dir * 16384;
        #pragma unroll
        for (int ks = 0; ks < 4; ++ks)
            af[ks] = *reinterpret_cast<const bf16x8*>(fb + ((mw*4 + ks)*64 + l)*8);
    }

    // init own state (+ bwd f32 state)
    f32x4 up;
    u32 ownprev0, ownprev1;
    float Cacc = 0.f;
    {
        const float* sv = dir ? endT : startT;
        const int t0 = dir ? 511 : 0;
        const f32x4 e4 = *reinterpret_cast<const f32x4*>(
            em + ((size_t)t0*Bn + batch)*Kn + bj + 8*g);
        const float* s4p = sv + bj + 8*g;
        f32x4 y;
        #pragma unroll
        for (int r = 0; r < 4; ++r) {
            const float s = s4p[r];
            y[r]  = __expf(s + e4[r]);
            up[r] = __expf(s);
        }
        ownprev0 = pack2bf(y[0], y[1]);
        ownprev1 = pack2bf(y[2], y[3]);
        u32* slot = reinterpret_cast<u32*>(&exchg[1][ksw][l]) + 2*half;
        u32x2 nw2 = {ownprev0, ownprev1};
        *reinterpret_cast<u32x2*>(slot) = nw2;   // iter m=1 reads parity 1
    }

    const int M = 256 - dir;

    // constant per-lane offsets (32-bit) + uniform t-offsets advanced on SALU.
    // 4 buffers; each buffer's offset advances 4t per use.
    const u32 laneE = (u32)((batch*Kn) + bj + 8*g);          // f32-index into em
    const u32 laneM = (u32)batch;                            // int-index into mask
    const long stepE = dir ? -(long)(4*Bn*Kn) : (long)(4*Bn*Kn);   // per 4t (f32 units)
    const long stepM = dir ? -(long)(4*Bn)    : (long)(4*Bn);      // per 4t (int units)
    long uE[4], uM[4];
    #pragma unroll
    for (int i = 0; i < 4; ++i) {
        const int tE = dir ? (511 - (1 + i)) : (1 + i);   // em t for m=1+i
        const int tM = dir ? (512 - (1 + i)) : (1 + i);   // mask t for m=1+i
        uE[i] = (long)tE * (Bn*Kn);
        uM[i] = (long)tM * Bn;
    }

    f32x4 e0, e1, e2, e3;
    int mk0, mk1, mk2, mk3;
    auto load_tile = [&](f32x4& ed, int& mk, long& uEi, long& uMi) {
        ed = *reinterpret_cast<const f32x4*>(em + uEi + laneE); uEi += stepE;
        mk = maskp[uMi + laneM]; uMi += stepM;
    };

    auto iter = [&](f32x4& ecur, int& mkcur, long& uEi, long& uMi, bool rs, int par) {
        // release own write of previous step, sync, read full state
        asm volatile("s_waitcnt lgkmcnt(0)" ::: "memory");
        __builtin_amdgcn_s_barrier();
        __builtin_amdgcn_sched_barrier(0);

        const u32x4 bs0 = exchg[par][0][l];
        const u32x4 bs1 = exchg[par][1][l];
        const u32x4 bs2 = exchg[par][2][l];
        const u32x4 bs3 = exchg[par][3][l];

        // 2 independent MFMA chains of 2, then add (halves serial MFMA latency)
        f32x4 a0 = {0.f, 0.f, 0.f, 0.f}, a1 = {0.f, 0.f, 0.f, 0.f};
        a0 = __builtin_amdgcn_mfma_f32_16x16x32_bf16(af[0], __builtin_bit_cast(bf16x8, bs0), a0, 0, 0, 0);
        a1 = __builtin_amdgcn_mfma_f32_16x16x32_bf16(af[2], __builtin_bit_cast(bf16x8, bs2), a1, 0, 0, 0);
        a0 = __builtin_amdgcn_mfma_f32_16x16x32_bf16(af[1], __builtin_bit_cast(bf16x8, bs1), a0, 0, 0, 0);
        a1 = __builtin_amdgcn_mfma_f32_16x16x32_bf16(af[3], __builtin_bit_cast(bf16x8, bs3), a1, 0, 0, 0);
        const f32x4 acc = a0 + a1;

        const bool mk = (mkcur != 0);
        float sc = 1.f, klog = 0.f;
        if (rs) {   // exact pow-2 rescale; exponent of batch c's k=0 state component
            int ex = (int)((bs0[0] >> 7) & 0xFF) - 127;
            ex = __shfl(ex, c, 64);
            sc = __uint_as_float((u32)((127 - ex) & 0xFF) << 23);
            klog = (float)ex * 0.6931471805599453f;
        }

        f32x4 xf;
        #pragma unroll
        for (int r = 0; r < 4; ++r) xf[r] = __expf(ecur[r]);

        u32 nw0, nw1;
        if (dir == 0) {  // fwd: v_t = (v@E)*x_t if mask else v
            f32x4 y;
            #pragma unroll
            for (int r = 0; r < 4; ++r) {
                float a = acc[r];
                if (rs) a *= sc;
                y[r] = a * xf[r];
            }
            nw0 = pack2bf(y[0], y[1]);
            nw1 = pack2bf(y[2], y[3]);
            nw0 = mk ? nw0 : ownprev0;
            nw1 = mk ? nw1 : ownprev1;
            ownprev0 = nw0; ownprev1 = nw1;
            if (rs && mk) Cacc += klog;
        } else {  // bwd: u = select(E@B, u); scale both branches; B = u*x_t
            f32x4 y;
            #pragma unroll
            for (int r = 0; r < 4; ++r) {
                float un = mk ? acc[r] : up[r];
                if (rs) un *= sc;
                up[r] = un;
                y[r] = un * xf[r];
            }
            nw0 = pack2bf(y[0], y[1]);
            nw1 = pack2bf(y[2], y[3]);
            if (rs) Cacc += klog;
        }

        u32* slot = reinterpret_cast<u32*>(&exchg[par ^ 1][ksw][l]) + 2*half;
        u32x2 nw2 = {nw0, nw1};
        *reinterpret_cast<u32x2*>(slot) = nw2;

        load_tile(ecur, mkcur, uEi, uMi);    // reload t = m+4 into the same buffer
        __builtin_amdgcn_sched_barrier(0xF); // ALU/VALU/SALU/MFMA may cross; VMEM+DS pinned
    };

    load_tile(e0, mk0, uE[0], uM[0]);        // m=1
    load_tile(e1, mk1, uE[1], uM[1]);        // m=2
    load_tile(e2, mk2, uE[2], uM[2]);        // m=3
    load_tile(e3, mk3, uE[3], uM[3]);        // m=4
    __builtin_amdgcn_sched_barrier(0xF);

    int m = 1;
    for (; m + 3 <= M; m += 4) {       // rs static: only (m+3)%4==0 rescales; par static
        iter(e0, mk0, uE[0], uM[0], false, 1);
        iter(e1, mk1, uE[1], uM[1], false, 0);
        iter(e2, mk2, uE[2], uM[2], false, 1);
        iter(e3, mk3, uE[3], uM[3], true,  0);
    }
    // tail (bwd: m=253..255; never a rescale step). Buffer index = (m-1)&3.
    for (; m <= M; ++m) {
        const int bi = (m - 1) & 3;
        const int par = m & 1;
        if      (bi == 0) iter(e0, mk0, uE[0], uM[0], false, par);
        else if (bi == 1) iter(e1, mk1, uE[1], uM[1], false, par);
        else              iter(e2, mk2, uE[2], uM[2], false, par);
    }

    // final own state: fwd from ownprev regs, bwd from f32 up.
    // Only lanes c<4 store (c>=4 are duplicates of batch c&3).
    if ((c >> 2) == 0) {
        float* vrow = vws + ((size_t)(dir*Bn + batch))*Kn + bj + 8*g;
        f32x4 fv;
        if (dir) {
            fv = up;
        } else {
            fv[0] = __uint_as_float(ownprev0 << 16);
            fv[1] = __uint_as_float(ownprev0 & 0xffff0000u);
            fv[2] = __uint_as_float(ownprev1 << 16);
            fv[3] = __uint_as_float(ownprev1 & 0xffff0000u);
        }
        *reinterpret_cast<f32x4*>(vrow) = fv;
        if (mw == 0 && g == 0) Cws[dir*Bn + batch] = Cacc;
    }
}

// ---------------- combine: numerator finalize + den + out accumulation ----------------
__global__ void crf_combine(const float* __restrict__ vws, const float* __restrict__ Cws,
                            const float* __restrict__ numpart, const int* __restrict__ cntpart,
                            const int* __restrict__ tags, const float* __restrict__ em,
                            const float* __restrict__ startT, const float* __restrict__ endT,
                            float* __restrict__ out)
{
    const int b = blockIdx.x;
    const int tid = threadIdx.x;
    const float p = vws[(size_t)b*Kn + tid] * vws[(size_t)(Bn + b)*Kn + tid];
    __shared__ float red[128];
    __shared__ float sp[NUMCH];
    __shared__ int   cp[NUMCH];
    red[tid] = p;
    if (tid < NUMCH) { sp[tid] = numpart[tid*Bn + b]; cp[tid] = cntpart[tid*Bn + b]; }
    __syncthreads();
    for (int off = 64; off > 0; off >>= 1) {
        if (tid < off) red[tid] += red[tid + off];
        __syncthreads();
    }
    if (tid == 0) {
        float s = 0.f; int cnt = 0;
        #pragma unroll
        for (int ch = 0; ch < NUMCH; ++ch) { s += sp[ch]; cnt += cp[ch]; }
        const int t0tag = tags[b];
        int seq_end = cnt - 1;
        if (seq_end < 0) seq_end = 0;
        const int lastTag = tags[seq_end*Bn + b];
        const float num = startT[t0tag] + em[(size_t)b*Kn + t0tag] + s + endT[lastTag];
        const float den = Cws[b] + Cws[Bn + b] + logf(red[0]);
        atomicAdd(out, num - den);
    }
}

extern "C" void kernel_launch(void* const* d_in, const int* in_sizes, int n_in,
                              void* d_out, int out_size, void* d_ws, size_t ws_size,
                              hipStream_t stream)
{
    const float* em     = (const float*)d_in[0];
    const int*   tags   = (const int*)d_in[1];
    const int*   mask   = (const int*)d_in[2];
    const float* startT = (const float*)d_in[3];
    const float* endT   = (const float*)d_in[4];
    const float* trans  = (const float*)d_in[5];

    char* ws = (char*)d_ws;
    bf16_t* frags   = (bf16_t*)ws;                    // 65536 B
    float*  Cws     = (float*)(ws + 65536);           // 4096 B
    float*  vws     = (float*)(ws + 69632);           // 524288 B
    float*  numpart = (float*)(ws + 593920);          // 32768 B
    int*    cntpart = (int*)(ws + 626688);            // 32768 B
    float*  out     = (float*)d_out;

    hipLaunchKernelGGL(crf_small, dim3(2*NUMCH + 128), dim3(256), 0, stream,
                       em, tags, mask, trans, frags, numpart, cntpart, out);
    hipLaunchKernelGGL(crf_main, dim3(256), dim3(512), 0, stream,
                       em, mask, startT, endT, frags, vws, Cws);
    hipLaunchKernelGGL(crf_combine, dim3(Bn), dim3(128), 0, stream,
                       vws, Cws, numpart, cntpart, tags, em, startT, endT, out);
}